// Round 1
// baseline (208.971 us; speedup 1.0000x reference)
//
#include <hip/hip_runtime.h>
#include <math.h>

// Problem constants (fixed by the reference)
constexpr int B = 16384;
constexpr int D = 128;   // state dim
constexpr int H = 128;   // hidden
constexpr int O = 32;    // options
constexpr int A = 64;    // actions

constexpr int NB = 4;    // samples per block
constexpr int NT = 128;  // threads per block

__global__ __launch_bounds__(NT) void bandit_fused(
    const float* __restrict__ state, const float* __restrict__ u,
    const float* __restrict__ opt_w1, const float* __restrict__ opt_b1,
    const float* __restrict__ opt_w2, const float* __restrict__ opt_b2,
    const float* __restrict__ exp_w1, const float* __restrict__ exp_b1,
    const float* __restrict__ exp_w2, const float* __restrict__ exp_b2,
    const float* __restrict__ term_w1, const float* __restrict__ term_b1,
    const float* __restrict__ term_w2, const float* __restrict__ term_b2,
    float* __restrict__ out_optp, float* __restrict__ out_actp,
    float* __restrict__ out_term, float* __restrict__ out_selopt,
    float* __restrict__ out_selact)
{
    __shared__ float s_state[NB][D];
    __shared__ float s_h[NB][H];
    __shared__ float s_probs[NB][O];
    __shared__ int   s_opt[NB];
    __shared__ float s_eh[H];
    __shared__ float s_part[2][A];
    __shared__ float s_red[NB][2];

    const int tid = threadIdx.x;
    const int b0  = blockIdx.x * NB;

    // ---- 1. stage state tile ----
    #pragma unroll
    for (int nb = 0; nb < NB; ++nb)
        s_state[nb][tid] = state[(size_t)(b0 + nb) * D + tid];
    __syncthreads();

    // ---- 2. option hidden: h = relu(state @ opt_w1 + b1) ----
    {
        float acc[NB];
        const float bias = opt_b1[tid];
        #pragma unroll
        for (int nb = 0; nb < NB; ++nb) acc[nb] = bias;
        for (int d = 0; d < D; ++d) {
            const float w = opt_w1[d * H + tid];       // coalesced across tid
            #pragma unroll
            for (int nb = 0; nb < NB; ++nb)
                acc[nb] = fmaf(s_state[nb][d], w, acc[nb]);
        }
        #pragma unroll
        for (int nb = 0; nb < NB; ++nb)
            s_h[nb][tid] = fmaxf(acc[nb], 0.f);
    }
    __syncthreads();

    // ---- 3. option logits + softmax: thread = nb*O + o ----
    {
        const int nb = tid >> 5;       // /32
        const int o  = tid & (O - 1);
        float acc = opt_b2[o];
        for (int h = 0; h < H; ++h)
            acc = fmaf(s_h[nb][h], opt_w2[h * O + o], acc);
        // softmax within a 32-lane group
        float m = acc;
        #pragma unroll
        for (int mask = 16; mask; mask >>= 1)
            m = fmaxf(m, __shfl_xor(m, mask, 32));
        const float e = expf(acc - m);
        float ssum = e;
        #pragma unroll
        for (int mask = 16; mask; mask >>= 1)
            ssum += __shfl_xor(ssum, mask, 32);
        const float p = e / ssum;
        s_probs[nb][o] = p;
        out_optp[(size_t)(b0 + nb) * O + o] = p;
    }
    __syncthreads();

    // ---- 4. inverse-CDF option selection (exact sequential cumsum) ----
    if (tid < NB) {
        const float uu = u[b0 + tid];
        float c = 0.f; int cnt = 0;
        for (int o = 0; o < O; ++o) {
            c += s_probs[tid][o];
            cnt += (c < uu) ? 1 : 0;
        }
        const int sel = (cnt < O - 1) ? cnt : (O - 1);
        s_opt[tid] = sel;
        out_selopt[b0 + tid] = (float)sel;
    }
    __syncthreads();

    // ---- 5. routed expert MLP, one sample at a time ----
    for (int nb = 0; nb < NB; ++nb) {
        const int o = s_opt[nb];
        // hidden: thread tid computes neuron tid
        {
            float acc = exp_b1[o * H + tid];
            const float* w1 = exp_w1 + (size_t)o * D * H;
            for (int d = 0; d < D; ++d)
                acc = fmaf(s_state[nb][d], w1[d * H + tid], acc);
            s_eh[tid] = fmaxf(acc, 0.f);
        }
        __syncthreads();
        // logits: split H over 2 halves; t = part*64 + a
        {
            const int a = tid & (A - 1);
            const int part = tid >> 6;
            const float* w2 = exp_w2 + (size_t)o * H * A;
            float acc = 0.f;
            const int h0 = part * 64;
            for (int h = h0; h < h0 + 64; ++h)
                acc = fmaf(s_eh[h], w2[h * A + a], acc);
            s_part[part][a] = acc;
        }
        __syncthreads();
        if (tid < A) {
            const float logit = s_part[0][tid] + s_part[1][tid] + exp_b2[o * A + tid];
            // softmax over 64 lanes (wave 0)
            float m = logit;
            #pragma unroll
            for (int mask = 32; mask; mask >>= 1)
                m = fmaxf(m, __shfl_xor(m, mask, 64));
            const float e = expf(logit - m);
            float ssum = e;
            #pragma unroll
            for (int mask = 32; mask; mask >>= 1)
                ssum += __shfl_xor(ssum, mask, 64);
            out_actp[(size_t)(b0 + nb) * A + tid] = e / ssum;
            // argmax, first-index tiebreak
            float bv = logit; int bi = tid;
            #pragma unroll
            for (int mask = 32; mask; mask >>= 1) {
                const float ov = __shfl_xor(bv, mask, 64);
                const int   oi = __shfl_xor(bi, mask, 64);
                if (ov > bv || (ov == bv && oi < bi)) { bv = ov; bi = oi; }
            }
            if (tid == 0) out_selact[b0 + nb] = (float)bi;
        }
        __syncthreads();
    }

    // ---- 6. termination head ----
    {
        float acc[NB];
        const float bias = term_b1[tid];
        #pragma unroll
        for (int nb = 0; nb < NB; ++nb) acc[nb] = bias;
        for (int d = 0; d < D; ++d) {
            const float w = term_w1[d * H + tid];
            #pragma unroll
            for (int nb = 0; nb < NB; ++nb)
                acc[nb] = fmaf(s_state[nb][d], w, acc[nb]);
        }
        const float w2 = term_w2[tid];
        float part[NB];
        #pragma unroll
        for (int nb = 0; nb < NB; ++nb)
            part[nb] = fmaxf(acc[nb], 0.f) * w2;

        const int lane = tid & 63, wv = tid >> 6;
        #pragma unroll
        for (int nb = 0; nb < NB; ++nb) {
            float v = part[nb];
            #pragma unroll
            for (int mask = 32; mask; mask >>= 1)
                v += __shfl_xor(v, mask, 64);
            if (lane == 0) s_red[nb][wv] = v;
        }
        __syncthreads();
        if (tid < NB) {
            const float x = s_red[tid][0] + s_red[tid][1] + term_b2[0];
            out_term[b0 + tid] = 1.f / (1.f + expf(-x));
        }
    }
}

extern "C" void kernel_launch(void* const* d_in, const int* in_sizes, int n_in,
                              void* d_out, int out_size, void* d_ws, size_t ws_size,
                              hipStream_t stream) {
    const float* state   = (const float*)d_in[0];
    const float* u       = (const float*)d_in[1];
    const float* opt_w1  = (const float*)d_in[2];
    const float* opt_b1  = (const float*)d_in[3];
    const float* opt_w2  = (const float*)d_in[4];
    const float* opt_b2  = (const float*)d_in[5];
    const float* exp_w1  = (const float*)d_in[6];
    const float* exp_b1  = (const float*)d_in[7];
    const float* exp_w2  = (const float*)d_in[8];
    const float* exp_b2  = (const float*)d_in[9];
    const float* term_w1 = (const float*)d_in[10];
    const float* term_b1 = (const float*)d_in[11];
    const float* term_w2 = (const float*)d_in[12];
    const float* term_b2 = (const float*)d_in[13];

    float* out = (float*)d_out;
    float* out_optp   = out;                        // [B, O]
    float* out_actp   = out_optp + (size_t)B * O;   // [B, A]
    float* out_term   = out_actp + (size_t)B * A;   // [B, 1]
    float* out_selopt = out_term + B;               // [B]
    float* out_selact = out_selopt + B;             // [B]

    dim3 grid(B / NB), block(NT);
    hipLaunchKernelGGL(bandit_fused, grid, block, 0, stream,
                       state, u, opt_w1, opt_b1, opt_w2, opt_b2,
                       exp_w1, exp_b1, exp_w2, exp_b2,
                       term_w1, term_b1, term_w2, term_b2,
                       out_optp, out_actp, out_term, out_selopt, out_selact);
}